// Round 6
// baseline (5516.639 us; speedup 1.0000x reference)
//
#include <hip/hip_runtime.h>
#include <hip/hip_bf16.h>
#include <math.h>

#define NODES 32768
#define DD 256
#define NE 524288
#define BATCH 64
#define SEQ 512

__device__ __forceinline__ float sigf(float x) { return 1.0f / (1.0f + expf(-x)); }

// ---------------- embedding: x = emb[tok] + wt[type] ----------------
__global__ __launch_bounds__(256) void embed_kernel(const int* __restrict__ tok,
                                                    const int* __restrict__ wty,
                                                    const float* __restrict__ emb,
                                                    const float* __restrict__ wt,
                                                    float* __restrict__ x) {
    int i = blockIdx.x;
    int d = threadIdx.x;
    x[i * DD + d] = emb[tok[i] * DD + d] + wt[wty[i] * DD + d];
}

// ---------------- plain GEMM: C[M,256] = A[M,256] @ B[256,256] (+bias)(tanh) ----------------
template <bool BIAS, bool TANH>
__global__ __launch_bounds__(256) void gemm_nn(const float* __restrict__ A,
                                               const float* __restrict__ B,
                                               const float* __restrict__ bias,
                                               float* __restrict__ C, int M) {
    __shared__ float As[16][68];
    __shared__ float Bs[16][68];
    const int m0 = blockIdx.x * 64;
    const int n0 = blockIdx.y * 64;
    const int t = threadIdx.x;
    const int ty = t >> 4, tx = t & 15;
    const int lm = t >> 2;          // 0..63
    const int lk4 = (t & 3) * 4;    // 0,4,8,12
    const int bkk = t >> 4;         // 0..15
    const int bn4 = (t & 15) * 4;   // 0..60

    float acc[4][4] = {};
    for (int k0 = 0; k0 < 256; k0 += 16) {
        float4 av = *(const float4*)&A[(m0 + lm) * 256 + k0 + lk4];
        float4 bv = *(const float4*)&B[(k0 + bkk) * 256 + n0 + bn4];
        __syncthreads();
        As[lk4 + 0][lm] = av.x; As[lk4 + 1][lm] = av.y;
        As[lk4 + 2][lm] = av.z; As[lk4 + 3][lm] = av.w;
        *(float4*)&Bs[bkk][bn4] = bv;
        __syncthreads();
#pragma unroll
        for (int kk = 0; kk < 16; ++kk) {
            float4 a = *(const float4*)&As[kk][ty * 4];
            float4 b = *(const float4*)&Bs[kk][tx * 4];
            float av4[4] = {a.x, a.y, a.z, a.w};
            float bv4[4] = {b.x, b.y, b.z, b.w};
#pragma unroll
            for (int i = 0; i < 4; ++i)
#pragma unroll
                for (int j = 0; j < 4; ++j)
                    acc[i][j] = fmaf(av4[i], bv4[j], acc[i][j]);
        }
    }
#pragma unroll
    for (int i = 0; i < 4; ++i) {
        int r = m0 + ty * 4 + i;
        float o[4];
#pragma unroll
        for (int j = 0; j < 4; ++j) {
            float v = acc[i][j];
            if (BIAS) v += bias[n0 + tx * 4 + j];
            if (TANH) v = tanhf(v);
            o[j] = v;
        }
        *(float4*)&C[r * 256 + n0 + tx * 4] = make_float4(o[0], o[1], o[2], o[3]);
    }
}

// ------------- fused LSTM gate GEMM + cell ---------------
template <bool FIRST>
__global__ __launch_bounds__(256) void lstm_gemm(const float* __restrict__ X,
                                                 const float* __restrict__ H,
                                                 const float* __restrict__ Wih,
                                                 const float* __restrict__ Whh,
                                                 const float* __restrict__ bih,
                                                 const float* __restrict__ bhh,
                                                 const float* __restrict__ c_in,
                                                 float* __restrict__ c_out,
                                                 float* __restrict__ h_out, int M) {
    __shared__ float As[16][68];
    __shared__ float Bs[4][16][68];
    const int m0 = blockIdx.x * 64;
    const int n0 = blockIdx.y * 64;  // d-column tile (0..255)
    const int t = threadIdx.x;
    const int ty = t >> 4, tx = t & 15;
    const int lm = t >> 2;
    const int lk4 = (t & 3) * 4;

    float acc[4][4][4] = {};  // [gate][i][j]
    const int npass = FIRST ? 1 : 2;
    for (int pass = 0; pass < npass; ++pass) {
        const float* Ain = pass ? H : X;
        const float* W = pass ? Whh : Wih;
        for (int k0 = 0; k0 < 256; k0 += 16) {
            float4 av = *(const float4*)&Ain[(m0 + lm) * 256 + k0 + lk4];
            float4 w0 = *(const float4*)&W[(0 * 256 + n0 + lm) * 256 + k0 + lk4];
            float4 w1 = *(const float4*)&W[(1 * 256 + n0 + lm) * 256 + k0 + lk4];
            float4 w2 = *(const float4*)&W[(2 * 256 + n0 + lm) * 256 + k0 + lk4];
            float4 w3 = *(const float4*)&W[(3 * 256 + n0 + lm) * 256 + k0 + lk4];
            __syncthreads();
            As[lk4 + 0][lm] = av.x; As[lk4 + 1][lm] = av.y;
            As[lk4 + 2][lm] = av.z; As[lk4 + 3][lm] = av.w;
            Bs[0][lk4 + 0][lm] = w0.x; Bs[0][lk4 + 1][lm] = w0.y;
            Bs[0][lk4 + 2][lm] = w0.z; Bs[0][lk4 + 3][lm] = w0.w;
            Bs[1][lk4 + 0][lm] = w1.x; Bs[1][lk4 + 1][lm] = w1.y;
            Bs[1][lk4 + 2][lm] = w1.z; Bs[1][lk4 + 3][lm] = w1.w;
            Bs[2][lk4 + 0][lm] = w2.x; Bs[2][lk4 + 1][lm] = w2.y;
            Bs[2][lk4 + 2][lm] = w2.z; Bs[2][lk4 + 3][lm] = w2.w;
            Bs[3][lk4 + 0][lm] = w3.x; Bs[3][lk4 + 1][lm] = w3.y;
            Bs[3][lk4 + 2][lm] = w3.z; Bs[3][lk4 + 3][lm] = w3.w;
            __syncthreads();
#pragma unroll
            for (int kk = 0; kk < 16; ++kk) {
                float4 a = *(const float4*)&As[kk][ty * 4];
                float av4[4] = {a.x, a.y, a.z, a.w};
#pragma unroll
                for (int g = 0; g < 4; ++g) {
                    float4 b = *(const float4*)&Bs[g][kk][tx * 4];
                    float bv4[4] = {b.x, b.y, b.z, b.w};
#pragma unroll
                    for (int i = 0; i < 4; ++i)
#pragma unroll
                        for (int j = 0; j < 4; ++j)
                            acc[g][i][j] = fmaf(av4[i], bv4[j], acc[g][i][j]);
                }
            }
        }
    }
#pragma unroll
    for (int i = 0; i < 4; ++i) {
        int r = m0 + ty * 4 + i;
#pragma unroll
        for (int j = 0; j < 4; ++j) {
            int dcol = n0 + tx * 4 + j;
            float gi = acc[0][i][j] + bih[dcol] + bhh[dcol];
            float gf = acc[1][i][j] + bih[256 + dcol] + bhh[256 + dcol];
            float gg = acc[2][i][j] + bih[512 + dcol] + bhh[512 + dcol];
            float go = acc[3][i][j] + bih[768 + dcol] + bhh[768 + dcol];
            float cprev = FIRST ? 0.0f : c_in[r * 256 + dcol];
            float cv = sigf(gf) * cprev + sigf(gi) * tanhf(gg);
            float hv = sigf(go) * tanhf(cv);
            c_out[r * 256 + dcol] = cv;
            h_out[r * 256 + dcol] = hv;
        }
    }
}

// ---------------- GCN degree / norm ----------------
__global__ __launch_bounds__(256) void deg_init(float* __restrict__ deg) {
    int i = blockIdx.x * 256 + threadIdx.x;
    deg[i] = 1.0f;  // self-loop weight
}
__global__ __launch_bounds__(256) void deg_scatter(const int* __restrict__ dst,
                                                   const float* __restrict__ ew,
                                                   float* __restrict__ deg) {
    int e = blockIdx.x * 256 + threadIdx.x;
    atomicAdd(&deg[dst[e]], ew[e]);
}
__global__ __launch_bounds__(256) void dinv_kernel(const float* __restrict__ deg,
                                                   float* __restrict__ dinv) {
    int i = blockIdx.x * 256 + threadIdx.x;
    dinv[i] = 1.0f / sqrtf(deg[i]);
}
// agg[i] = dinv[i]^2 * x[i]   (self-loop term, also zero-initializes agg)
__global__ __launch_bounds__(256) void gcn_selfinit(const float* __restrict__ x,
                                                    const float* __restrict__ dinv,
                                                    float* __restrict__ agg) {
    int i = blockIdx.x;
    int d = threadIdx.x;
    float di = dinv[i];
    agg[i * DD + d] = di * di * x[i * DD + d];
}
// agg[dst] += dinv[src]*ew*dinv[dst] * x[src]   (4 edges per block, 64 lanes/edge)
__global__ __launch_bounds__(256) void gcn_scatter(const float* __restrict__ x,
                                                   const int* __restrict__ src,
                                                   const int* __restrict__ dst,
                                                   const float* __restrict__ ew,
                                                   const float* __restrict__ dinv,
                                                   float* __restrict__ agg) {
    int e = blockIdx.x * 4 + (threadIdx.x >> 6);
    int l = threadIdx.x & 63;
    int s = src[e], d = dst[e];
    float nrm = dinv[s] * ew[e] * dinv[d];
    float4 v = *(const float4*)&x[s * DD + l * 4];
    float* o = &agg[d * DD + l * 4];
    atomicAdd(o + 0, nrm * v.x);
    atomicAdd(o + 1, nrm * v.y);
    atomicAdd(o + 2, nrm * v.z);
    atomicAdd(o + 3, nrm * v.w);
}

// ---------------- pooling ----------------
__global__ __launch_bounds__(256) void score_kernel(const float* __restrict__ htmp,
                                                    const float* __restrict__ Wp2,
                                                    const float* __restrict__ mask_score,
                                                    float* __restrict__ score) {
    int m = blockIdx.x * 4 + (threadIdx.x >> 6);
    int l = threadIdx.x & 63;
    float4 h = *(const float4*)&htmp[m * DD + l * 4];
    float4 w = *(const float4*)&Wp2[l * 4];
    float d = h.x * w.x + h.y * w.y + h.z * w.z + h.w * w.w;
#pragma unroll
    for (int off = 32; off; off >>= 1) d += __shfl_down(d, off);
    if (l == 0) score[m] = d + mask_score[m];
}

// softmax over N=512 per batch + weighted sum -> g[b, 256]
__global__ __launch_bounds__(256) void pool_kernel(const float* __restrict__ x,
                                                   const float* __restrict__ score,
                                                   float* __restrict__ gout) {
    int b = blockIdx.x;
    int t = threadIdx.x;
    __shared__ float sal[512];
    __shared__ float wred[4];
    __shared__ float sbc[2];
    int lane = t & 63, wv = t >> 6;
    float s0 = score[b * SEQ + t];
    float s1 = score[b * SEQ + 256 + t];
    float m = fmaxf(s0, s1);
#pragma unroll
    for (int off = 32; off; off >>= 1) m = fmaxf(m, __shfl_down(m, off));
    if (lane == 0) wred[wv] = m;
    __syncthreads();
    if (t == 0) sbc[0] = fmaxf(fmaxf(wred[0], wred[1]), fmaxf(wred[2], wred[3]));
    __syncthreads();
    float mx = sbc[0];
    float e0 = expf(s0 - mx), e1 = expf(s1 - mx);
    sal[t] = e0;
    sal[t + 256] = e1;
    float sm = e0 + e1;
#pragma unroll
    for (int off = 32; off; off >>= 1) sm += __shfl_down(sm, off);
    __syncthreads();  // wred[max] consumed; safe to overwrite
    if (lane == 0) wred[wv] = sm;
    __syncthreads();
    if (t == 0) sbc[1] = wred[0] + wred[1] + wred[2] + wred[3];
    __syncthreads();
    float inv = 1.0f / sbc[1];
    float accv = 0.0f;
    const float* xb = x + (size_t)b * SEQ * DD + t;
    for (int n = 0; n < SEQ; ++n) accv += sal[n] * xb[n * DD];
    gout[b * DD + t] = accv * inv;
}

// ---------------- final: out = tanh(x2) * mask_pad ----------------
__global__ __launch_bounds__(256) void final_kernel(const float* __restrict__ x2,
                                                    const float* __restrict__ mask_pad,
                                                    float* __restrict__ out) {
    int i = blockIdx.x;
    int d = threadIdx.x;
    out[i * DD + d] = tanhf(x2[i * DD + d]) * mask_pad[i];
}

extern "C" void kernel_launch(void* const* d_in, const int* in_sizes, int n_in,
                              void* d_out, int out_size, void* d_ws, size_t ws_size,
                              hipStream_t stream) {
    const int* x_tokens = (const int*)d_in[0];
    const int* word_type = (const int*)d_in[1];
    const int* edge_src = (const int*)d_in[2];
    const int* edge_dst = edge_src + NE;
    const float* edge_attr = (const float*)d_in[3];
    const float* mask_pad = (const float*)d_in[4];
    const float* mask_score = (const float*)d_in[5];
    const float* emb = (const float*)d_in[6];
    const float* wt = (const float*)d_in[7];
    const float* W_w = (const float*)d_in[8];
    const float* b_w = (const float*)d_in[9];
    const float* W_g1 = (const float*)d_in[10];
    const float* b_g1 = (const float*)d_in[11];
    const float* W_g2 = (const float*)d_in[12];
    const float* b_g2 = (const float*)d_in[13];
    const float* W_p1 = (const float*)d_in[14];
    const float* b_p1 = (const float*)d_in[15];
    const float* W_p2 = (const float*)d_in[16];
    const float* Wih_x = (const float*)d_in[17];
    const float* Whh_x = (const float*)d_in[18];
    const float* bih_x = (const float*)d_in[19];
    const float* bhh_x = (const float*)d_in[20];
    const float* Wih_g = (const float*)d_in[21];
    const float* Whh_g = (const float*)d_in[22];
    const float* bih_g = (const float*)d_in[23];
    const float* bhh_g = (const float*)d_in[24];

    float* out = (float*)d_out;
    char* ws = (char*)d_ws;

    // ---- workspace layout: smalls first (640 KiB), then 3 node buffers (96 MiB).
    // Total ws usage: ~97 MiB (was 168.6 MiB — round-5 post-timing failure diagnosed
    // as ws overflow corrupting harness pristine-input copies).
    float* fw = (float*)ws;
    float* deg = fw;                     // 32768
    float* dinv = deg + NODES;           // 32768
    float* score = dinv + NODES;         // 32768
    float* g1 = score + NODES;           // 16384
    float* g2 = g1 + BATCH * DD;         // 16384
    float* hg = g2 + BATCH * DD;         // 16384
    float* cg = hg + BATCH * DD;         // 16384  (end = 163840 floats = 640 KiB)
    const size_t NDf = (size_t)NODES * DD;  // floats per node buffer
    float* base = (float*)(ws + (1 << 20));
    float* B1 = base;
    float* B2 = base + NDf;
    float* B3 = base + 2 * NDf;
    // c-state lives in the x_out region of d_out (exactly NODES*DD floats);
    // final_kernel overwrites it at the very end.
    float* OUTB = out;

    dim3 blk(256);
    dim3 gemmGrid(NODES / 64, 4);

    // x_emb -> B1
    embed_kernel<<<NODES, blk, 0, stream>>>(x_tokens, word_type, emb, wt, B1);
    // x0 = x_emb @ W_w + b_w -> B2
    gemm_nn<true, false><<<gemmGrid, blk, 0, stream>>>(B1, W_w, b_w, B2, NODES);
    // degrees / symmetric norm
    deg_init<<<NODES / 256, blk, 0, stream>>>(deg);
    deg_scatter<<<NE / 256, blk, 0, stream>>>(edge_dst, edge_attr, deg);
    dinv_kernel<<<NODES / 256, blk, 0, stream>>>(deg, dinv);
    // agg0 = Ahat * x0 -> B1  (x_emb dead)
    gcn_selfinit<<<NODES, blk, 0, stream>>>(B2, dinv, B1);
    gcn_scatter<<<NE / 4, blk, 0, stream>>>(B2, edge_src, edge_dst, edge_attr, dinv, B1);
    // x1_mid = agg0 @ W_g1 + b_g1 -> B3
    gemm_nn<true, false><<<gemmGrid, blk, 0, stream>>>(B1, W_g1, b_g1, B3, NODES);
    // LSTM1 cell1(x0=B2) -> h1:B1 (agg0 dead), c1:OUTB
    lstm_gemm<true><<<gemmGrid, blk, 0, stream>>>(B2, nullptr, Wih_x, Whh_x, bih_x, bhh_x,
                                                  nullptr, OUTB, B1, NODES);
    // LSTM1 cell2(x1_mid=B3, h1=B1, c=OUTB) -> x1:B2 (x0 dead), c:OUTB (in-place)
    lstm_gemm<false><<<gemmGrid, blk, 0, stream>>>(B3, B1, Wih_x, Whh_x, bih_x, bhh_x,
                                                   OUTB, OUTB, B2, NODES);
    // pool 1: htmp = tanh(x1@Wp1+bp1) -> B3 (x1_mid dead); score; g1
    gemm_nn<true, true><<<gemmGrid, blk, 0, stream>>>(B2, W_p1, b_p1, B3, NODES);
    score_kernel<<<NODES / 4, blk, 0, stream>>>(B3, W_p2, mask_score, score);
    pool_kernel<<<BATCH, blk, 0, stream>>>(B2, score, g1);
    // agg1 = Ahat * x1 -> B1 (h1 dead)
    gcn_selfinit<<<NODES, blk, 0, stream>>>(B2, dinv, B1);
    gcn_scatter<<<NE / 4, blk, 0, stream>>>(B2, edge_src, edge_dst, edge_attr, dinv, B1);
    // x2_mid = agg1 @ W_g2 + b_g2 -> B3 (htmp1 dead)
    gemm_nn<true, false><<<gemmGrid, blk, 0, stream>>>(B1, W_g2, b_g2, B3, NODES);
    // LSTM2 cell1(x1=B2) -> h2:B1 (agg1 dead), c2:OUTB (c1 dead)
    lstm_gemm<true><<<gemmGrid, blk, 0, stream>>>(B2, nullptr, Wih_x, Whh_x, bih_x, bhh_x,
                                                  nullptr, OUTB, B1, NODES);
    // LSTM2 cell2(x2_mid=B3, h2=B1, c=OUTB) -> x2:B2 (x1 dead), c:OUTB
    lstm_gemm<false><<<gemmGrid, blk, 0, stream>>>(B3, B1, Wih_x, Whh_x, bih_x, bhh_x,
                                                   OUTB, OUTB, B2, NODES);
    // pool 2: htmp -> B3 ; score ; g2
    gemm_nn<true, true><<<gemmGrid, blk, 0, stream>>>(B2, W_p1, b_p1, B3, NODES);
    score_kernel<<<NODES / 4, blk, 0, stream>>>(B3, W_p2, mask_score, score);
    pool_kernel<<<BATCH, blk, 0, stream>>>(B2, score, g2);
    // graph-level LSTM over (g1, g2) -> graph_out region of d_out
    lstm_gemm<true><<<dim3(1, 4), blk, 0, stream>>>(g1, nullptr, Wih_g, Whh_g, bih_g, bhh_g,
                                                    nullptr, cg, hg, BATCH);
    lstm_gemm<false><<<dim3(1, 4), blk, 0, stream>>>(g2, hg, Wih_g, Whh_g, bih_g, bhh_g,
                                                     cg, cg, out + NODES * DD, BATCH);
    // x_out = tanh(x2=B2) * mask_pad -> overwrites c-scratch in d_out
    final_kernel<<<NODES, blk, 0, stream>>>(B2, mask_pad, out);
}

// Round 8
// 2245.250 us; speedup vs baseline: 2.4570x; 2.4570x over previous
//
#include <hip/hip_runtime.h>
#include <hip/hip_bf16.h>
#include <math.h>

#define NODES 32768
#define DD 256
#define NE 524288
#define BATCH 64
#define SEQ 512

__device__ __forceinline__ float sigf(float x) { return 1.0f / (1.0f + expf(-x)); }

// ---------------- embedding: x = emb[tok] + wt[type] ----------------
__global__ __launch_bounds__(256) void embed_kernel(const int* __restrict__ tok,
                                                    const int* __restrict__ wty,
                                                    const float* __restrict__ emb,
                                                    const float* __restrict__ wt,
                                                    float* __restrict__ x) {
    int i = blockIdx.x;
    int d = threadIdx.x;
    x[i * DD + d] = emb[tok[i] * DD + d] + wt[wty[i] * DD + d];
}

// ---------------- plain GEMM: C[M,256] = A[M,256] @ B[256,256] (+bias)(tanh) ----------------
template <bool BIAS, bool TANH>
__global__ __launch_bounds__(256) void gemm_nn(const float* __restrict__ A,
                                               const float* __restrict__ B,
                                               const float* __restrict__ bias,
                                               float* __restrict__ C, int M) {
    __shared__ float As[16][68];
    __shared__ float Bs[16][68];
    const int m0 = blockIdx.x * 64;
    const int n0 = blockIdx.y * 64;
    const int t = threadIdx.x;
    const int ty = t >> 4, tx = t & 15;
    const int lm = t >> 2;          // 0..63
    const int lk4 = (t & 3) * 4;    // 0,4,8,12
    const int bkk = t >> 4;         // 0..15
    const int bn4 = (t & 15) * 4;   // 0..60

    float acc[4][4] = {};
    for (int k0 = 0; k0 < 256; k0 += 16) {
        float4 av = *(const float4*)&A[(m0 + lm) * 256 + k0 + lk4];
        float4 bv = *(const float4*)&B[(k0 + bkk) * 256 + n0 + bn4];
        __syncthreads();
        As[lk4 + 0][lm] = av.x; As[lk4 + 1][lm] = av.y;
        As[lk4 + 2][lm] = av.z; As[lk4 + 3][lm] = av.w;
        *(float4*)&Bs[bkk][bn4] = bv;
        __syncthreads();
#pragma unroll
        for (int kk = 0; kk < 16; ++kk) {
            float4 a = *(const float4*)&As[kk][ty * 4];
            float4 b = *(const float4*)&Bs[kk][tx * 4];
            float av4[4] = {a.x, a.y, a.z, a.w};
            float bv4[4] = {b.x, b.y, b.z, b.w};
#pragma unroll
            for (int i = 0; i < 4; ++i)
#pragma unroll
                for (int j = 0; j < 4; ++j)
                    acc[i][j] = fmaf(av4[i], bv4[j], acc[i][j]);
        }
    }
#pragma unroll
    for (int i = 0; i < 4; ++i) {
        int r = m0 + ty * 4 + i;
        float o[4];
#pragma unroll
        for (int j = 0; j < 4; ++j) {
            float v = acc[i][j];
            if (BIAS) v += bias[n0 + tx * 4 + j];
            if (TANH) v = tanhf(v);
            o[j] = v;
        }
        *(float4*)&C[r * 256 + n0 + tx * 4] = make_float4(o[0], o[1], o[2], o[3]);
    }
}

// ------------- fused LSTM gate GEMM + cell ---------------
template <bool FIRST>
__global__ __launch_bounds__(256) void lstm_gemm(const float* __restrict__ X,
                                                 const float* __restrict__ H,
                                                 const float* __restrict__ Wih,
                                                 const float* __restrict__ Whh,
                                                 const float* __restrict__ bih,
                                                 const float* __restrict__ bhh,
                                                 const float* __restrict__ c_in,
                                                 float* __restrict__ c_out,
                                                 float* __restrict__ h_out, int M) {
    __shared__ float As[16][68];
    __shared__ float Bs[4][16][68];
    const int m0 = blockIdx.x * 64;
    const int n0 = blockIdx.y * 64;  // d-column tile (0..255)
    const int t = threadIdx.x;
    const int ty = t >> 4, tx = t & 15;
    const int lm = t >> 2;
    const int lk4 = (t & 3) * 4;

    float acc[4][4][4] = {};  // [gate][i][j]
    const int npass = FIRST ? 1 : 2;
    for (int pass = 0; pass < npass; ++pass) {
        const float* Ain = pass ? H : X;
        const float* W = pass ? Whh : Wih;
        for (int k0 = 0; k0 < 256; k0 += 16) {
            float4 av = *(const float4*)&Ain[(m0 + lm) * 256 + k0 + lk4];
            float4 w0 = *(const float4*)&W[(0 * 256 + n0 + lm) * 256 + k0 + lk4];
            float4 w1 = *(const float4*)&W[(1 * 256 + n0 + lm) * 256 + k0 + lk4];
            float4 w2 = *(const float4*)&W[(2 * 256 + n0 + lm) * 256 + k0 + lk4];
            float4 w3 = *(const float4*)&W[(3 * 256 + n0 + lm) * 256 + k0 + lk4];
            __syncthreads();
            As[lk4 + 0][lm] = av.x; As[lk4 + 1][lm] = av.y;
            As[lk4 + 2][lm] = av.z; As[lk4 + 3][lm] = av.w;
            Bs[0][lk4 + 0][lm] = w0.x; Bs[0][lk4 + 1][lm] = w0.y;
            Bs[0][lk4 + 2][lm] = w0.z; Bs[0][lk4 + 3][lm] = w0.w;
            Bs[1][lk4 + 0][lm] = w1.x; Bs[1][lk4 + 1][lm] = w1.y;
            Bs[1][lk4 + 2][lm] = w1.z; Bs[1][lk4 + 3][lm] = w1.w;
            Bs[2][lk4 + 0][lm] = w2.x; Bs[2][lk4 + 1][lm] = w2.y;
            Bs[2][lk4 + 2][lm] = w2.z; Bs[2][lk4 + 3][lm] = w2.w;
            Bs[3][lk4 + 0][lm] = w3.x; Bs[3][lk4 + 1][lm] = w3.y;
            Bs[3][lk4 + 2][lm] = w3.z; Bs[3][lk4 + 3][lm] = w3.w;
            __syncthreads();
#pragma unroll
            for (int kk = 0; kk < 16; ++kk) {
                float4 a = *(const float4*)&As[kk][ty * 4];
                float av4[4] = {a.x, a.y, a.z, a.w};
#pragma unroll
                for (int g = 0; g < 4; ++g) {
                    float4 b = *(const float4*)&Bs[g][kk][tx * 4];
                    float bv4[4] = {b.x, b.y, b.z, b.w};
#pragma unroll
                    for (int i = 0; i < 4; ++i)
#pragma unroll
                        for (int j = 0; j < 4; ++j)
                            acc[g][i][j] = fmaf(av4[i], bv4[j], acc[g][i][j]);
                }
            }
        }
    }
#pragma unroll
    for (int i = 0; i < 4; ++i) {
        int r = m0 + ty * 4 + i;
#pragma unroll
        for (int j = 0; j < 4; ++j) {
            int dcol = n0 + tx * 4 + j;
            float gi = acc[0][i][j] + bih[dcol] + bhh[dcol];
            float gf = acc[1][i][j] + bih[256 + dcol] + bhh[256 + dcol];
            float gg = acc[2][i][j] + bih[512 + dcol] + bhh[512 + dcol];
            float go = acc[3][i][j] + bih[768 + dcol] + bhh[768 + dcol];
            float cprev = FIRST ? 0.0f : c_in[r * 256 + dcol];
            float cv = sigf(gf) * cprev + sigf(gi) * tanhf(gg);
            float hv = sigf(go) * tanhf(cv);
            c_out[r * 256 + dcol] = cv;
            h_out[r * 256 + dcol] = hv;
        }
    }
}

// ---------------- CSR build (graph identical for both GCN layers: build once) ----------------
__global__ __launch_bounds__(256) void csr_init(int* __restrict__ counts, float* __restrict__ deg) {
    int i = blockIdx.x * 256 + threadIdx.x;
    counts[i] = 0;
    deg[i] = 1.0f;
}
__global__ __launch_bounds__(256) void csr_hist(const int* __restrict__ dst,
                                                const float* __restrict__ ew,
                                                int* __restrict__ counts,
                                                float* __restrict__ deg) {
    int e = blockIdx.x * 256 + threadIdx.x;
    int d = dst[e];
    atomicAdd(&counts[d], 1);
    atomicAdd(&deg[d], ew[e]);
}
__global__ __launch_bounds__(256) void csr_dinv(float* __restrict__ deg) {
    int i = blockIdx.x * 256 + threadIdx.x;
    deg[i] = 1.0f / sqrtf(deg[i]);
}
// exclusive scan of counts[32768] -> offs[32769]; cursor = offs copy. One block, 256 thr x 128 elems.
__global__ __launch_bounds__(256) void csr_scan(const int* __restrict__ counts,
                                                int* __restrict__ offs,
                                                int* __restrict__ cursor) {
    __shared__ int part[256];
    int t = threadIdx.x;
    int base = t * 128;
    int s = 0;
    for (int k = 0; k < 128; ++k) s += counts[base + k];
    part[t] = s;
    __syncthreads();
    for (int off = 1; off < 256; off <<= 1) {
        int v = part[t];
        int add = (t >= off) ? part[t - off] : 0;
        __syncthreads();
        part[t] = v + add;
        __syncthreads();
    }
    int run = part[t] - s;  // exclusive prefix of this segment
    for (int k = 0; k < 128; ++k) {
        int c = counts[base + k];
        offs[base + k] = run;
        cursor[base + k] = run;
        run += c;
    }
    if (t == 255) offs[NODES] = run;
}
// counting-sort edges by dst; precompute norm = dinv[src]*ew*dinv[dst]
__global__ __launch_bounds__(256) void csr_fill(const int* __restrict__ src,
                                                const int* __restrict__ dst,
                                                const float* __restrict__ ew,
                                                const float* __restrict__ dinv,
                                                int* __restrict__ cursor,
                                                int* __restrict__ es,
                                                float* __restrict__ en) {
    int e = blockIdx.x * 256 + threadIdx.x;
    int s = src[e], d = dst[e];
    int pos = atomicAdd(&cursor[d], 1);
    es[pos] = s;
    en[pos] = dinv[s] * ew[e] * dinv[d];
}

// ---------------- GCN aggregate by gather: agg[i] = dinv[i]^2*x[i] + sum_j norm_j*x[src_j] ----
__global__ __launch_bounds__(256) void gcn_gather(const float* __restrict__ x,
                                                  const int* __restrict__ offs,
                                                  const int* __restrict__ es,
                                                  const float* __restrict__ en,
                                                  const float* __restrict__ dinv,
                                                  float* __restrict__ agg) {
    int i = blockIdx.x;
    int d = threadIdx.x;
    float di = dinv[i];
    float acc = di * di * x[i * DD + d];
    int a = offs[i], b = offs[i + 1];
    for (int j = a; j < b; ++j) {
        int s = es[j];      // broadcast (all lanes same address)
        float w = en[j];    // broadcast
        acc += w * x[s * DD + d];  // coalesced 1KB row
    }
    agg[i * DD + d] = acc;
}

// ---------------- pooling ----------------
__global__ __launch_bounds__(256) void score_kernel(const float* __restrict__ htmp,
                                                    const float* __restrict__ Wp2,
                                                    const float* __restrict__ mask_score,
                                                    float* __restrict__ score) {
    int m = blockIdx.x * 4 + (threadIdx.x >> 6);
    int l = threadIdx.x & 63;
    float4 h = *(const float4*)&htmp[m * DD + l * 4];
    float4 w = *(const float4*)&Wp2[l * 4];
    float d = h.x * w.x + h.y * w.y + h.z * w.z + h.w * w.w;
#pragma unroll
    for (int off = 32; off; off >>= 1) d += __shfl_down(d, off);
    if (l == 0) score[m] = d + mask_score[m];
}

// softmax over N=512 per batch + weighted sum -> g[b, 256]
__global__ __launch_bounds__(256) void pool_kernel(const float* __restrict__ x,
                                                   const float* __restrict__ score,
                                                   float* __restrict__ gout) {
    int b = blockIdx.x;
    int t = threadIdx.x;
    __shared__ float sal[512];
    __shared__ float wred[4];
    __shared__ float sbc[2];
    int lane = t & 63, wv = t >> 6;
    float s0 = score[b * SEQ + t];
    float s1 = score[b * SEQ + 256 + t];
    float m = fmaxf(s0, s1);
#pragma unroll
    for (int off = 32; off; off >>= 1) m = fmaxf(m, __shfl_down(m, off));
    if (lane == 0) wred[wv] = m;
    __syncthreads();
    if (t == 0) sbc[0] = fmaxf(fmaxf(wred[0], wred[1]), fmaxf(wred[2], wred[3]));
    __syncthreads();
    float mx = sbc[0];
    float e0 = expf(s0 - mx), e1 = expf(s1 - mx);
    sal[t] = e0;
    sal[t + 256] = e1;
    float sm = e0 + e1;
#pragma unroll
    for (int off = 32; off; off >>= 1) sm += __shfl_down(sm, off);
    __syncthreads();
    if (lane == 0) wred[wv] = sm;
    __syncthreads();
    if (t == 0) sbc[1] = wred[0] + wred[1] + wred[2] + wred[3];
    __syncthreads();
    float inv = 1.0f / sbc[1];
    float accv = 0.0f;
    const float* xb = x + (size_t)b * SEQ * DD + t;
    for (int n = 0; n < SEQ; ++n) accv += sal[n] * xb[n * DD];
    gout[b * DD + t] = accv * inv;
}

// ---------------- final: out = tanh(x2) * mask_pad ----------------
__global__ __launch_bounds__(256) void final_kernel(const float* __restrict__ x2,
                                                    const float* __restrict__ mask_pad,
                                                    float* __restrict__ out) {
    int i = blockIdx.x;
    int d = threadIdx.x;
    out[i * DD + d] = tanhf(x2[i * DD + d]) * mask_pad[i];
}

extern "C" void kernel_launch(void* const* d_in, const int* in_sizes, int n_in,
                              void* d_out, int out_size, void* d_ws, size_t ws_size,
                              hipStream_t stream) {
    const int* x_tokens = (const int*)d_in[0];
    const int* word_type = (const int*)d_in[1];
    const int* edge_src = (const int*)d_in[2];
    const int* edge_dst = edge_src + NE;
    const float* edge_attr = (const float*)d_in[3];
    const float* mask_pad = (const float*)d_in[4];
    const float* mask_score = (const float*)d_in[5];
    const float* emb = (const float*)d_in[6];
    const float* wt = (const float*)d_in[7];
    const float* W_w = (const float*)d_in[8];
    const float* b_w = (const float*)d_in[9];
    const float* W_g1 = (const float*)d_in[10];
    const float* b_g1 = (const float*)d_in[11];
    const float* W_g2 = (const float*)d_in[12];
    const float* b_g2 = (const float*)d_in[13];
    const float* W_p1 = (const float*)d_in[14];
    const float* b_p1 = (const float*)d_in[15];
    const float* W_p2 = (const float*)d_in[16];
    const float* Wih_x = (const float*)d_in[17];
    const float* Whh_x = (const float*)d_in[18];
    const float* bih_x = (const float*)d_in[19];
    const float* bhh_x = (const float*)d_in[20];
    const float* Wih_g = (const float*)d_in[21];
    const float* Whh_g = (const float*)d_in[22];
    const float* bih_g = (const float*)d_in[23];
    const float* bhh_g = (const float*)d_in[24];

    float* out = (float*)d_out;
    char* ws = (char*)d_ws;

    // ---- workspace layout (~102 MB): smalls+CSR in first 6 MB, then 3 node buffers.
    int* counts = (int*)ws;                       // 32768 ints
    int* cursor = counts + NODES;                 // 32768 ints
    int* offs = cursor + NODES;                   // 32769 ints (+pad)
    float* dinv = (float*)(offs + NODES + 64);    // 32768 f (deg in-place)
    float* score = dinv + NODES;                  // 32768 f
    float* g1 = score + NODES;                    // 16384 f
    float* g2 = g1 + BATCH * DD;
    float* hg = g2 + BATCH * DD;
    float* cg = hg + BATCH * DD;
    int* es = (int*)(cg + BATCH * DD);            // 524288 ints (2 MB)
    float* en = (float*)(es + NE);                // 524288 f    (2 MB)
    const size_t NDf = (size_t)NODES * DD;
    float* base = (float*)(ws + (6u << 20));
    float* B1 = base;
    float* B2 = base + NDf;
    float* B3 = base + 2 * NDf;
    float* OUTB = out;  // c-state scratch in x_out region; final_kernel overwrites

    dim3 blk(256);
    dim3 gemmGrid(NODES / 64, 4);

    // ---- CSR build (once; shared by both GCN layers) ----
    csr_init<<<NODES / 256, blk, 0, stream>>>(counts, dinv);
    csr_hist<<<NE / 256, blk, 0, stream>>>(edge_dst, edge_attr, counts, dinv);
    csr_dinv<<<NODES / 256, blk, 0, stream>>>(dinv);
    csr_scan<<<1, blk, 0, stream>>>(counts, offs, cursor);
    csr_fill<<<NE / 256, blk, 0, stream>>>(edge_src, edge_dst, edge_attr, dinv, cursor, es, en);

    // x_emb -> B1
    embed_kernel<<<NODES, blk, 0, stream>>>(x_tokens, word_type, emb, wt, B1);
    // x0 = x_emb @ W_w + b_w -> B2
    gemm_nn<true, false><<<gemmGrid, blk, 0, stream>>>(B1, W_w, b_w, B2, NODES);
    // agg0 = Ahat * x0 -> B1 (x_emb dead)
    gcn_gather<<<NODES, blk, 0, stream>>>(B2, offs, es, en, dinv, B1);
    // x1_mid = agg0 @ W_g1 + b_g1 -> B3
    gemm_nn<true, false><<<gemmGrid, blk, 0, stream>>>(B1, W_g1, b_g1, B3, NODES);
    // LSTM1 cell1(x0=B2) -> h1:B1 (agg0 dead), c1:OUTB
    lstm_gemm<true><<<gemmGrid, blk, 0, stream>>>(B2, nullptr, Wih_x, Whh_x, bih_x, bhh_x,
                                                  nullptr, OUTB, B1, NODES);
    // LSTM1 cell2(x1_mid=B3, h1=B1, c=OUTB) -> x1:B2 (x0 dead), c:OUTB
    lstm_gemm<false><<<gemmGrid, blk, 0, stream>>>(B3, B1, Wih_x, Whh_x, bih_x, bhh_x,
                                                   OUTB, OUTB, B2, NODES);
    // pool 1: htmp = tanh(x1@Wp1+bp1) -> B3; score; g1
    gemm_nn<true, true><<<gemmGrid, blk, 0, stream>>>(B2, W_p1, b_p1, B3, NODES);
    score_kernel<<<NODES / 4, blk, 0, stream>>>(B3, W_p2, mask_score, score);
    pool_kernel<<<BATCH, blk, 0, stream>>>(B2, score, g1);
    // agg1 = Ahat * x1 -> B1 (h1 dead)
    gcn_gather<<<NODES, blk, 0, stream>>>(B2, offs, es, en, dinv, B1);
    // x2_mid = agg1 @ W_g2 + b_g2 -> B3 (htmp dead)
    gemm_nn<true, false><<<gemmGrid, blk, 0, stream>>>(B1, W_g2, b_g2, B3, NODES);
    // LSTM2 cell1(x1=B2) -> h2:B1 (agg1 dead), c2:OUTB (c1 dead)
    lstm_gemm<true><<<gemmGrid, blk, 0, stream>>>(B2, nullptr, Wih_x, Whh_x, bih_x, bhh_x,
                                                  nullptr, OUTB, B1, NODES);
    // LSTM2 cell2(x2_mid=B3, h2=B1, c=OUTB) -> x2:B2 (x1 dead), c:OUTB
    lstm_gemm<false><<<gemmGrid, blk, 0, stream>>>(B3, B1, Wih_x, Whh_x, bih_x, bhh_x,
                                                   OUTB, OUTB, B2, NODES);
    // pool 2: htmp -> B3 ; score ; g2
    gemm_nn<true, true><<<gemmGrid, blk, 0, stream>>>(B2, W_p1, b_p1, B3, NODES);
    score_kernel<<<NODES / 4, blk, 0, stream>>>(B3, W_p2, mask_score, score);
    pool_kernel<<<BATCH, blk, 0, stream>>>(B2, score, g2);
    // graph-level LSTM over (g1, g2) -> graph_out region of d_out
    lstm_gemm<true><<<dim3(1, 4), blk, 0, stream>>>(g1, nullptr, Wih_g, Whh_g, bih_g, bhh_g,
                                                    nullptr, cg, hg, BATCH);
    lstm_gemm<false><<<dim3(1, 4), blk, 0, stream>>>(g2, hg, Wih_g, Whh_g, bih_g, bhh_g,
                                                     cg, cg, out + NODES * DD, BATCH);
    // x_out = tanh(x2=B2) * mask_pad -> overwrites c-scratch in d_out
    final_kernel<<<NODES, blk, 0, stream>>>(B2, mask_pad, out);
}

// Round 9
// 2117.616 us; speedup vs baseline: 2.6051x; 1.0603x over previous
//
#include <hip/hip_runtime.h>
#include <hip/hip_bf16.h>
#include <math.h>

#define NODES 32768
#define DD 256
#define NE 524288
#define BATCH 64
#define SEQ 512

typedef __attribute__((ext_vector_type(8))) short short8v;
typedef __attribute__((ext_vector_type(4))) float f32x4;
typedef unsigned short u16;

__device__ __forceinline__ float sigf(float x) { return 1.0f / (1.0f + expf(-x)); }
__device__ __forceinline__ float bfu(u16 u) {
    unsigned int x = ((unsigned int)u) << 16;
    float f;
    __builtin_memcpy(&f, &x, 4);
    return f;
}
__device__ __forceinline__ u16 f2b(float f) {
    __hip_bfloat16 h = __float2bfloat16(f);
    u16 u;
    __builtin_memcpy(&u, &h, 2);
    return u;
}
__device__ __forceinline__ void split_store(float v, u16* __restrict__ hi, u16* __restrict__ lo, int idx) {
    u16 h = f2b(v);
    hi[idx] = h;
    lo[idx] = f2b(v - bfu(h));
}

// ---------------- weight split converts ----------------
// W given [K=256][N=256] row-major (x @ W); emit BT layout [n][k], hi/lo bf16
__global__ __launch_bounds__(256) void wsplitT(const float* __restrict__ W,
                                               u16* __restrict__ h, u16* __restrict__ l) {
    int n = blockIdx.x, k = threadIdx.x;
    split_store(W[k * 256 + n], h, l, n * 256 + k);
}
// W given [N][K] row-major already (Wih: gates = x @ Wih^T)
__global__ __launch_bounds__(256) void wsplit(const float* __restrict__ W,
                                              u16* __restrict__ h, u16* __restrict__ l) {
    int i = blockIdx.x * 256 + threadIdx.x;
    split_store(W[i], h, l, i);
}

// ---------------- embedding -> split ----------------
__global__ __launch_bounds__(256) void embed_split(const int* __restrict__ tok,
                                                   const int* __restrict__ wty,
                                                   const float* __restrict__ emb,
                                                   const float* __restrict__ wt,
                                                   u16* __restrict__ xh, u16* __restrict__ xl) {
    int i = blockIdx.x, d = threadIdx.x;
    float v = emb[tok[i] * DD + d] + wt[wty[i] * DD + d];
    split_store(v, xh, xl, i * DD + d);
}

// ---------------- split-bf16 MFMA GEMM: C[M,256] = A[M,256] @ B, +bias (,tanh) ----------------
// A split [M][256] hi/lo; B split BT layout [256n][256k] hi/lo. Out: split.
// block 256 thr = 4 waves; wave w covers cols [w*64, w*64+64); block rows [bx*64, +64).
template <bool TANH>
__global__ __launch_bounds__(256) void mfma_gemm(const u16* __restrict__ Ah, const u16* __restrict__ Al,
                                                 const u16* __restrict__ Bh, const u16* __restrict__ Bl,
                                                 const float* __restrict__ bias,
                                                 u16* __restrict__ Chi, u16* __restrict__ Clo) {
    const int l = threadIdx.x & 63, w = threadIdx.x >> 6;
    const int m0 = blockIdx.x * 64, n0 = w * 64;
    const int lr = l & 15, lk = (l >> 4) * 8;
    f32x4 acc[4][4];
#pragma unroll
    for (int mi = 0; mi < 4; ++mi)
#pragma unroll
        for (int ni = 0; ni < 4; ++ni) acc[mi][ni] = (f32x4){0.f, 0.f, 0.f, 0.f};

    const u16* APtr[3] = {Ah, Ah, Al};
    const u16* BPtr[3] = {Bh, Bl, Bh};
    for (int term = 0; term < 3; ++term) {
        const u16* A = APtr[term];
        const u16* B = BPtr[term];
#pragma unroll
        for (int kb = 0; kb < 8; ++kb) {
            int ka = kb * 32 + lk;
            short8v a[4], b[4];
#pragma unroll
            for (int mi = 0; mi < 4; ++mi)
                a[mi] = *(const short8v*)&A[(m0 + mi * 16 + lr) * 256 + ka];
#pragma unroll
            for (int ni = 0; ni < 4; ++ni)
                b[ni] = *(const short8v*)&B[(n0 + ni * 16 + lr) * 256 + ka];
#pragma unroll
            for (int mi = 0; mi < 4; ++mi)
#pragma unroll
                for (int ni = 0; ni < 4; ++ni)
                    acc[mi][ni] = __builtin_amdgcn_mfma_f32_16x16x32_bf16(a[mi], b[ni], acc[mi][ni], 0, 0, 0);
        }
    }
#pragma unroll
    for (int mi = 0; mi < 4; ++mi)
#pragma unroll
        for (int ni = 0; ni < 4; ++ni) {
            int col = n0 + ni * 16 + lr;
            float bs = bias[col];
#pragma unroll
            for (int r = 0; r < 4; ++r) {
                int row = m0 + mi * 16 + (l >> 4) * 4 + r;
                float v = acc[mi][ni][r] + bs;
                if (TANH) v = tanhf(v);
                split_store(v, Chi, Clo, row * 256 + col);
            }
        }
}

// ---------------- split-bf16 MFMA LSTM (fused gates GEMM + cell) ----------------
// wave w computes gate w over (64 rows x 64 dcols); LDS exchange; cell epilogue.
template <bool FIRST>
__global__ __launch_bounds__(256) void mfma_lstm(const u16* __restrict__ Xh, const u16* __restrict__ Xl,
                                                 const u16* __restrict__ Hh, const u16* __restrict__ Hl,
                                                 const u16* __restrict__ Wih_h, const u16* __restrict__ Wih_l,
                                                 const u16* __restrict__ Whh_h, const u16* __restrict__ Whh_l,
                                                 const float* __restrict__ bih, const float* __restrict__ bhh,
                                                 const float* __restrict__ c_in, float* __restrict__ c_out,
                                                 u16* __restrict__ Ohi, u16* __restrict__ Olo) {
    __shared__ float lds[4][64][65];
    const int l = threadIdx.x & 63, g = threadIdx.x >> 6;
    const int m0 = blockIdx.x * 64, d0 = blockIdx.y * 64;
    const int lr = l & 15, lk = (l >> 4) * 8;
    f32x4 acc[4][4];
#pragma unroll
    for (int mi = 0; mi < 4; ++mi)
#pragma unroll
        for (int ni = 0; ni < 4; ++ni) acc[mi][ni] = (f32x4){0.f, 0.f, 0.f, 0.f};

    const int npass = FIRST ? 1 : 2;
    for (int pass = 0; pass < npass; ++pass) {
        const u16* Ih = pass ? Hh : Xh;
        const u16* Il = pass ? Hl : Xl;
        const u16* Wh = pass ? Whh_h : Wih_h;
        const u16* Wl = pass ? Whh_l : Wih_l;
        const u16* APtr[3] = {Ih, Ih, Il};
        const u16* BPtr[3] = {Wh, Wl, Wh};
        for (int term = 0; term < 3; ++term) {
            const u16* A = APtr[term];
            const u16* B = BPtr[term];
#pragma unroll
            for (int kb = 0; kb < 8; ++kb) {
                int ka = kb * 32 + lk;
                short8v a[4], b[4];
#pragma unroll
                for (int mi = 0; mi < 4; ++mi)
                    a[mi] = *(const short8v*)&A[(m0 + mi * 16 + lr) * 256 + ka];
#pragma unroll
                for (int ni = 0; ni < 4; ++ni)
                    b[ni] = *(const short8v*)&B[(g * 256 + d0 + ni * 16 + lr) * 256 + ka];
#pragma unroll
                for (int mi = 0; mi < 4; ++mi)
#pragma unroll
                    for (int ni = 0; ni < 4; ++ni)
                        acc[mi][ni] = __builtin_amdgcn_mfma_f32_16x16x32_bf16(a[mi], b[ni], acc[mi][ni], 0, 0, 0);
            }
        }
    }
#pragma unroll
    for (int mi = 0; mi < 4; ++mi)
#pragma unroll
        for (int ni = 0; ni < 4; ++ni)
#pragma unroll
            for (int r = 0; r < 4; ++r)
                lds[g][mi * 16 + (l >> 4) * 4 + r][ni * 16 + lr] = acc[mi][ni][r];
    __syncthreads();
#pragma unroll 4
    for (int rep = 0; rep < 16; ++rep) {
        int idx = rep * 256 + threadIdx.x;
        int ml = idx >> 6, dl = idx & 63;
        int row = m0 + ml, d = d0 + dl;
        float gi = lds[0][ml][dl] + bih[d] + bhh[d];
        float gf = lds[1][ml][dl] + bih[256 + d] + bhh[256 + d];
        float gg = lds[2][ml][dl] + bih[512 + d] + bhh[512 + d];
        float go = lds[3][ml][dl] + bih[768 + d] + bhh[768 + d];
        float cprev = FIRST ? 0.0f : c_in[row * 256 + d];
        float cv = sigf(gf) * cprev + sigf(gi) * tanhf(gg);
        float hv = sigf(go) * tanhf(cv);
        c_out[row * 256 + d] = cv;
        split_store(hv, Ohi, Olo, row * 256 + d);
    }
}

// ---------------- fp32 LSTM (graph-level only, M=64) ----------------
template <bool FIRST>
__global__ __launch_bounds__(256) void lstm_gemm(const float* __restrict__ X,
                                                 const float* __restrict__ H,
                                                 const float* __restrict__ Wih,
                                                 const float* __restrict__ Whh,
                                                 const float* __restrict__ bih,
                                                 const float* __restrict__ bhh,
                                                 const float* __restrict__ c_in,
                                                 float* __restrict__ c_out,
                                                 float* __restrict__ h_out, int M) {
    __shared__ float As[16][68];
    __shared__ float Bs[4][16][68];
    const int m0 = blockIdx.x * 64;
    const int n0 = blockIdx.y * 64;
    const int t = threadIdx.x;
    const int ty = t >> 4, tx = t & 15;
    const int lm = t >> 2;
    const int lk4 = (t & 3) * 4;
    float acc[4][4][4] = {};
    const int npass = FIRST ? 1 : 2;
    for (int pass = 0; pass < npass; ++pass) {
        const float* Ain = pass ? H : X;
        const float* W = pass ? Whh : Wih;
        for (int k0 = 0; k0 < 256; k0 += 16) {
            float4 av = *(const float4*)&Ain[(m0 + lm) * 256 + k0 + lk4];
            float4 w0 = *(const float4*)&W[(0 * 256 + n0 + lm) * 256 + k0 + lk4];
            float4 w1 = *(const float4*)&W[(1 * 256 + n0 + lm) * 256 + k0 + lk4];
            float4 w2 = *(const float4*)&W[(2 * 256 + n0 + lm) * 256 + k0 + lk4];
            float4 w3 = *(const float4*)&W[(3 * 256 + n0 + lm) * 256 + k0 + lk4];
            __syncthreads();
            As[lk4 + 0][lm] = av.x; As[lk4 + 1][lm] = av.y;
            As[lk4 + 2][lm] = av.z; As[lk4 + 3][lm] = av.w;
            Bs[0][lk4 + 0][lm] = w0.x; Bs[0][lk4 + 1][lm] = w0.y;
            Bs[0][lk4 + 2][lm] = w0.z; Bs[0][lk4 + 3][lm] = w0.w;
            Bs[1][lk4 + 0][lm] = w1.x; Bs[1][lk4 + 1][lm] = w1.y;
            Bs[1][lk4 + 2][lm] = w1.z; Bs[1][lk4 + 3][lm] = w1.w;
            Bs[2][lk4 + 0][lm] = w2.x; Bs[2][lk4 + 1][lm] = w2.y;
            Bs[2][lk4 + 2][lm] = w2.z; Bs[2][lk4 + 3][lm] = w2.w;
            Bs[3][lk4 + 0][lm] = w3.x; Bs[3][lk4 + 1][lm] = w3.y;
            Bs[3][lk4 + 2][lm] = w3.z; Bs[3][lk4 + 3][lm] = w3.w;
            __syncthreads();
#pragma unroll
            for (int kk = 0; kk < 16; ++kk) {
                float4 a = *(const float4*)&As[kk][ty * 4];
                float av4[4] = {a.x, a.y, a.z, a.w};
#pragma unroll
                for (int gg = 0; gg < 4; ++gg) {
                    float4 b = *(const float4*)&Bs[gg][kk][tx * 4];
                    float bv4[4] = {b.x, b.y, b.z, b.w};
#pragma unroll
                    for (int i = 0; i < 4; ++i)
#pragma unroll
                        for (int j = 0; j < 4; ++j)
                            acc[gg][i][j] = fmaf(av4[i], bv4[j], acc[gg][i][j]);
                }
            }
        }
    }
#pragma unroll
    for (int i = 0; i < 4; ++i) {
        int r = m0 + ty * 4 + i;
#pragma unroll
        for (int j = 0; j < 4; ++j) {
            int dcol = n0 + tx * 4 + j;
            float gi = acc[0][i][j] + bih[dcol] + bhh[dcol];
            float gf = acc[1][i][j] + bih[256 + dcol] + bhh[256 + dcol];
            float gg = acc[2][i][j] + bih[512 + dcol] + bhh[512 + dcol];
            float go = acc[3][i][j] + bih[768 + dcol] + bhh[768 + dcol];
            float cprev = FIRST ? 0.0f : c_in[r * 256 + dcol];
            float cv = sigf(gf) * cprev + sigf(gi) * tanhf(gg);
            float hv = sigf(go) * tanhf(cv);
            c_out[r * 256 + dcol] = cv;
            h_out[r * 256 + dcol] = hv;
        }
    }
}

// ---------------- CSR build ----------------
__global__ __launch_bounds__(256) void csr_init(int* __restrict__ counts, float* __restrict__ deg) {
    int i = blockIdx.x * 256 + threadIdx.x;
    counts[i] = 0;
    deg[i] = 1.0f;
}
__global__ __launch_bounds__(256) void csr_hist(const int* __restrict__ dst,
                                                const float* __restrict__ ew,
                                                int* __restrict__ counts,
                                                float* __restrict__ deg) {
    int e = blockIdx.x * 256 + threadIdx.x;
    int d = dst[e];
    atomicAdd(&counts[d], 1);
    atomicAdd(&deg[d], ew[e]);
}
__global__ __launch_bounds__(256) void csr_dinv(float* __restrict__ deg) {
    int i = blockIdx.x * 256 + threadIdx.x;
    deg[i] = 1.0f / sqrtf(deg[i]);
}
__global__ __launch_bounds__(256) void csr_scan(const int* __restrict__ counts,
                                                int* __restrict__ offs,
                                                int* __restrict__ cursor) {
    __shared__ int part[256];
    int t = threadIdx.x;
    int base = t * 128;
    int s = 0;
    for (int k = 0; k < 128; ++k) s += counts[base + k];
    part[t] = s;
    __syncthreads();
    for (int off = 1; off < 256; off <<= 1) {
        int v = part[t];
        int add = (t >= off) ? part[t - off] : 0;
        __syncthreads();
        part[t] = v + add;
        __syncthreads();
    }
    int run = part[t] - s;
    for (int k = 0; k < 128; ++k) {
        int c = counts[base + k];
        offs[base + k] = run;
        cursor[base + k] = run;
        run += c;
    }
    if (t == 255) offs[NODES] = run;
}
__global__ __launch_bounds__(256) void csr_fill(const int* __restrict__ src,
                                                const int* __restrict__ dst,
                                                const float* __restrict__ ew,
                                                const float* __restrict__ dinv,
                                                int* __restrict__ cursor,
                                                int* __restrict__ es,
                                                float* __restrict__ en) {
    int e = blockIdx.x * 256 + threadIdx.x;
    int s = src[e], d = dst[e];
    int pos = atomicAdd(&cursor[d], 1);
    es[pos] = s;
    en[pos] = dinv[s] * ew[e] * dinv[d];
}

// ---------------- GCN gather (split in, split out) ----------------
__global__ __launch_bounds__(256) void gcn_gather(const u16* __restrict__ xh, const u16* __restrict__ xl,
                                                  const int* __restrict__ offs,
                                                  const int* __restrict__ es,
                                                  const float* __restrict__ en,
                                                  const float* __restrict__ dinv,
                                                  u16* __restrict__ oh, u16* __restrict__ ol) {
    int i = blockIdx.x, d = threadIdx.x;
    float di = dinv[i];
    float acc = di * di * (bfu(xh[i * DD + d]) + bfu(xl[i * DD + d]));
    int a = offs[i], b = offs[i + 1];
    for (int j = a; j < b; ++j) {
        int s = es[j];
        float w = en[j];
        acc += w * (bfu(xh[s * DD + d]) + bfu(xl[s * DD + d]));
    }
    split_store(acc, oh, ol, i * DD + d);
}

// ---------------- pooling (split x) ----------------
__global__ __launch_bounds__(256) void score_kernel(const u16* __restrict__ hh, const u16* __restrict__ hl,
                                                    const float* __restrict__ Wp2,
                                                    const float* __restrict__ mask_score,
                                                    float* __restrict__ score) {
    int m = blockIdx.x * 4 + (threadIdx.x >> 6);
    int l = threadIdx.x & 63;
    ushort4 a = *(const ushort4*)&hh[m * DD + l * 4];
    ushort4 b = *(const ushort4*)&hl[m * DD + l * 4];
    float4 w = *(const float4*)&Wp2[l * 4];
    float d = (bfu(a.x) + bfu(b.x)) * w.x + (bfu(a.y) + bfu(b.y)) * w.y +
              (bfu(a.z) + bfu(b.z)) * w.z + (bfu(a.w) + bfu(b.w)) * w.w;
#pragma unroll
    for (int off = 32; off; off >>= 1) d += __shfl_down(d, off);
    if (l == 0) score[m] = d + mask_score[m];
}

__global__ __launch_bounds__(256) void pool_kernel(const u16* __restrict__ xh, const u16* __restrict__ xl,
                                                   const float* __restrict__ score,
                                                   float* __restrict__ gout) {
    int b = blockIdx.x;
    int t = threadIdx.x;
    __shared__ float sal[512];
    __shared__ float wred[4];
    __shared__ float sbc[2];
    int lane = t & 63, wv = t >> 6;
    float s0 = score[b * SEQ + t];
    float s1 = score[b * SEQ + 256 + t];
    float m = fmaxf(s0, s1);
#pragma unroll
    for (int off = 32; off; off >>= 1) m = fmaxf(m, __shfl_down(m, off));
    if (lane == 0) wred[wv] = m;
    __syncthreads();
    if (t == 0) sbc[0] = fmaxf(fmaxf(wred[0], wred[1]), fmaxf(wred[2], wred[3]));
    __syncthreads();
    float mx = sbc[0];
    float e0 = expf(s0 - mx), e1 = expf(s1 - mx);
    sal[t] = e0;
    sal[t + 256] = e1;
    float sm = e0 + e1;
#pragma unroll
    for (int off = 32; off; off >>= 1) sm += __shfl_down(sm, off);
    __syncthreads();
    if (lane == 0) wred[wv] = sm;
    __syncthreads();
    if (t == 0) sbc[1] = wred[0] + wred[1] + wred[2] + wred[3];
    __syncthreads();
    float inv = 1.0f / sbc[1];
    float accv = 0.0f;
    size_t base = (size_t)b * SEQ * DD + t;
    for (int n = 0; n < SEQ; ++n)
        accv += sal[n] * (bfu(xh[base + (size_t)n * DD]) + bfu(xl[base + (size_t)n * DD]));
    gout[b * DD + t] = accv * inv;
}

// ---------------- final: out = tanh(x2) * mask_pad ----------------
__global__ __launch_bounds__(256) void final_kernel(const u16* __restrict__ xh, const u16* __restrict__ xl,
                                                    const float* __restrict__ mask_pad,
                                                    float* __restrict__ out) {
    int i = blockIdx.x, d = threadIdx.x;
    float v = bfu(xh[i * DD + d]) + bfu(xl[i * DD + d]);
    out[i * DD + d] = tanhf(v) * mask_pad[i];
}

extern "C" void kernel_launch(void* const* d_in, const int* in_sizes, int n_in,
                              void* d_out, int out_size, void* d_ws, size_t ws_size,
                              hipStream_t stream) {
    const int* x_tokens = (const int*)d_in[0];
    const int* word_type = (const int*)d_in[1];
    const int* edge_src = (const int*)d_in[2];
    const int* edge_dst = edge_src + NE;
    const float* edge_attr = (const float*)d_in[3];
    const float* mask_pad = (const float*)d_in[4];
    const float* mask_score = (const float*)d_in[5];
    const float* emb = (const float*)d_in[6];
    const float* wt = (const float*)d_in[7];
    const float* W_w = (const float*)d_in[8];
    const float* b_w = (const float*)d_in[9];
    const float* W_g1 = (const float*)d_in[10];
    const float* b_g1 = (const float*)d_in[11];
    const float* W_g2 = (const float*)d_in[12];
    const float* b_g2 = (const float*)d_in[13];
    const float* W_p1 = (const float*)d_in[14];
    const float* b_p1 = (const float*)d_in[15];
    const float* W_p2 = (const float*)d_in[16];
    const float* Wih_x = (const float*)d_in[17];
    const float* Whh_x = (const float*)d_in[18];
    const float* bih_x = (const float*)d_in[19];
    const float* bhh_x = (const float*)d_in[20];
    const float* Wih_g = (const float*)d_in[21];
    const float* Whh_g = (const float*)d_in[22];
    const float* bih_g = (const float*)d_in[23];
    const float* bhh_g = (const float*)d_in[24];

    float* out = (float*)d_out;
    char* ws = (char*)d_ws;

    // ---- smalls / CSR / weight-splits in first 8 MB ----
    int* counts = (int*)ws;                      // 32768
    int* cursor = counts + NODES;                // 32768
    int* offs = cursor + NODES;                  // 32769 (+pad to 64)
    float* dinv = (float*)(offs + NODES + 64);   // 32768
    float* score = dinv + NODES;                 // 32768
    float* g1 = score + NODES;                   // 16384
    float* g2 = g1 + BATCH * DD;
    float* hg = g2 + BATCH * DD;
    float* cg = hg + BATCH * DD;
    int* es = (int*)(cg + BATCH * DD);           // 524288
    float* en = (float*)(es + NE);               // 524288
    u16* wsm = (u16*)(en + NE);
    u16* wwTh = wsm;               u16* wwTl = wwTh + 65536;
    u16* wg1h = wwTl + 65536;      u16* wg1l = wg1h + 65536;
    u16* wg2h = wg1l + 65536;      u16* wg2l = wg2h + 65536;
    u16* wp1h = wg2l + 65536;      u16* wp1l = wp1h + 65536;
    u16* wihh = wp1l + 65536;      u16* wihl = wihh + 262144;
    u16* whhh = wihl + 262144;     u16* whhl = whhh + 262144;  // ends < 8 MB

    // ---- split node buffers (hi plane | lo plane), 32 MB each ----
    const size_t NDf = (size_t)NODES * DD;
    u16* base = (u16*)(ws + (8u << 20));
    u16* S1h = base;               u16* S1l = S1h + NDf;
    u16* S2h = S1l + NDf;          u16* S2l = S2h + NDf;
    u16* S3h = S2l + NDf;          u16* S3l = S3h + NDf;
    float* OUTB = out;  // fp32 c-state scratch in x_out region; final overwrites

    dim3 blk(256);
    dim3 gemmGrid(NODES / 64);
    dim3 lstmGrid(NODES / 64, 4);

    // CSR build
    csr_init<<<NODES / 256, blk, 0, stream>>>(counts, dinv);
    csr_hist<<<NE / 256, blk, 0, stream>>>(edge_dst, edge_attr, counts, dinv);
    csr_dinv<<<NODES / 256, blk, 0, stream>>>(dinv);
    csr_scan<<<1, blk, 0, stream>>>(counts, offs, cursor);
    csr_fill<<<NE / 256, blk, 0, stream>>>(edge_src, edge_dst, edge_attr, dinv, cursor, es, en);

    // weight splits
    wsplitT<<<256, blk, 0, stream>>>(W_w, wwTh, wwTl);
    wsplitT<<<256, blk, 0, stream>>>(W_g1, wg1h, wg1l);
    wsplitT<<<256, blk, 0, stream>>>(W_g2, wg2h, wg2l);
    wsplitT<<<256, blk, 0, stream>>>(W_p1, wp1h, wp1l);
    wsplit<<<1024, blk, 0, stream>>>(Wih_x, wihh, wihl);
    wsplit<<<1024, blk, 0, stream>>>(Whh_x, whhh, whhl);

    // x_emb -> S1
    embed_split<<<NODES, blk, 0, stream>>>(x_tokens, word_type, emb, wt, S1h, S1l);
    // x0 = x_emb @ W_w + b_w -> S2
    mfma_gemm<false><<<gemmGrid, blk, 0, stream>>>(S1h, S1l, wwTh, wwTl, b_w, S2h, S2l);
    // agg0 -> S1
    gcn_gather<<<NODES, blk, 0, stream>>>(S2h, S2l, offs, es, en, dinv, S1h, S1l);
    // x1_mid = agg0 @ W_g1 + b_g1 -> S3
    mfma_gemm<false><<<gemmGrid, blk, 0, stream>>>(S1h, S1l, wg1h, wg1l, b_g1, S3h, S3l);
    // LSTM1 cell1(x0=S2) -> h1:S1, c1:OUTB
    mfma_lstm<true><<<lstmGrid, blk, 0, stream>>>(S2h, S2l, nullptr, nullptr, wihh, wihl, whhh, whhl,
                                                  bih_x, bhh_x, nullptr, OUTB, S1h, S1l);
    // LSTM1 cell2(x1_mid=S3, h1=S1) -> x1:S2, c:OUTB
    mfma_lstm<false><<<lstmGrid, blk, 0, stream>>>(S3h, S3l, S1h, S1l, wihh, wihl, whhh, whhl,
                                                   bih_x, bhh_x, OUTB, OUTB, S2h, S2l);
    // pool 1
    mfma_gemm<true><<<gemmGrid, blk, 0, stream>>>(S2h, S2l, wp1h, wp1l, b_p1, S3h, S3l);
    score_kernel<<<NODES / 4, blk, 0, stream>>>(S3h, S3l, W_p2, mask_score, score);
    pool_kernel<<<BATCH, blk, 0, stream>>>(S2h, S2l, score, g1);
    // agg1 -> S1
    gcn_gather<<<NODES, blk, 0, stream>>>(S2h, S2l, offs, es, en, dinv, S1h, S1l);
    // x2_mid = agg1 @ W_g2 + b_g2 -> S3
    mfma_gemm<false><<<gemmGrid, blk, 0, stream>>>(S1h, S1l, wg2h, wg2l, b_g2, S3h, S3l);
    // LSTM2 cell1(x1=S2) -> h2:S1, c2:OUTB
    mfma_lstm<true><<<lstmGrid, blk, 0, stream>>>(S2h, S2l, nullptr, nullptr, wihh, wihl, whhh, whhl,
                                                  bih_x, bhh_x, nullptr, OUTB, S1h, S1l);
    // LSTM2 cell2(x2_mid=S3, h2=S1) -> x2:S2, c:OUTB
    mfma_lstm<false><<<lstmGrid, blk, 0, stream>>>(S3h, S3l, S1h, S1l, wihh, wihl, whhh, whhl,
                                                   bih_x, bhh_x, OUTB, OUTB, S2h, S2l);
    // pool 2
    mfma_gemm<true><<<gemmGrid, blk, 0, stream>>>(S2h, S2l, wp1h, wp1l, b_p1, S3h, S3l);
    score_kernel<<<NODES / 4, blk, 0, stream>>>(S3h, S3l, W_p2, mask_score, score);
    pool_kernel<<<BATCH, blk, 0, stream>>>(S2h, S2l, score, g2);
    // graph-level LSTM (fp32, tiny)
    lstm_gemm<true><<<dim3(1, 4), blk, 0, stream>>>(g1, nullptr, Wih_g, Whh_g, bih_g, bhh_g,
                                                    nullptr, cg, hg, BATCH);
    lstm_gemm<false><<<dim3(1, 4), blk, 0, stream>>>(g2, hg, Wih_g, Whh_g, bih_g, bhh_g,
                                                     cg, cg, out + NODES * DD, BATCH);
    // x_out
    final_kernel<<<NODES, blk, 0, stream>>>(S2h, S2l, mask_pad, out);
}

// Round 10
// 1852.146 us; speedup vs baseline: 2.9785x; 1.1433x over previous
//
#include <hip/hip_runtime.h>
#include <hip/hip_bf16.h>
#include <math.h>

#define NODES 32768
#define DD 256
#define NE 524288
#define BATCH 64
#define SEQ 512

typedef __attribute__((ext_vector_type(8))) short short8v;
typedef __attribute__((ext_vector_type(4))) float f32x4;
typedef unsigned short u16;

__device__ __forceinline__ float sigf(float x) { return 1.0f / (1.0f + expf(-x)); }
__device__ __forceinline__ float bfu(u16 u) {
    unsigned int x = ((unsigned int)u) << 16;
    float f;
    __builtin_memcpy(&f, &x, 4);
    return f;
}
__device__ __forceinline__ u16 f2b(float f) {
    __hip_bfloat16 h = __float2bfloat16(f);
    u16 u;
    __builtin_memcpy(&u, &h, 2);
    return u;
}
__device__ __forceinline__ void split_store(float v, u16* __restrict__ hi, u16* __restrict__ lo, int idx) {
    u16 h = f2b(v);
    hi[idx] = h;
    lo[idx] = f2b(v - bfu(h));
}

// ---------------- weight split converts ----------------
__global__ __launch_bounds__(256) void wsplitT(const float* __restrict__ W,
                                               u16* __restrict__ h, u16* __restrict__ l) {
    int n = blockIdx.x, k = threadIdx.x;
    split_store(W[k * 256 + n], h, l, n * 256 + k);
}
__global__ __launch_bounds__(256) void wsplit(const float* __restrict__ W,
                                              u16* __restrict__ h, u16* __restrict__ l) {
    int i = blockIdx.x * 256 + threadIdx.x;
    split_store(W[i], h, l, i);
}

// ---------------- embedding -> split ----------------
__global__ __launch_bounds__(256) void embed_split(const int* __restrict__ tok,
                                                   const int* __restrict__ wty,
                                                   const float* __restrict__ emb,
                                                   const float* __restrict__ wt,
                                                   u16* __restrict__ xh, u16* __restrict__ xl) {
    int i = blockIdx.x, d = threadIdx.x;
    float v = emb[tok[i] * DD + d] + wt[wty[i] * DD + d];
    split_store(v, xh, xl, i * DD + d);
}

// ---------------- split-bf16 MFMA GEMM (unchanged from round 9) ----------------
template <bool TANH>
__global__ __launch_bounds__(256) void mfma_gemm(const u16* __restrict__ Ah, const u16* __restrict__ Al,
                                                 const u16* __restrict__ Bh, const u16* __restrict__ Bl,
                                                 const float* __restrict__ bias,
                                                 u16* __restrict__ Chi, u16* __restrict__ Clo) {
    const int l = threadIdx.x & 63, w = threadIdx.x >> 6;
    const int m0 = blockIdx.x * 64, n0 = w * 64;
    const int lr = l & 15, lk = (l >> 4) * 8;
    f32x4 acc[4][4];
#pragma unroll
    for (int mi = 0; mi < 4; ++mi)
#pragma unroll
        for (int ni = 0; ni < 4; ++ni) acc[mi][ni] = (f32x4){0.f, 0.f, 0.f, 0.f};

    const u16* APtr[3] = {Ah, Ah, Al};
    const u16* BPtr[3] = {Bh, Bl, Bh};
    for (int term = 0; term < 3; ++term) {
        const u16* A = APtr[term];
        const u16* B = BPtr[term];
#pragma unroll
        for (int kb = 0; kb < 8; ++kb) {
            int ka = kb * 32 + lk;
            short8v a[4], b[4];
#pragma unroll
            for (int mi = 0; mi < 4; ++mi)
                a[mi] = *(const short8v*)&A[(m0 + mi * 16 + lr) * 256 + ka];
#pragma unroll
            for (int ni = 0; ni < 4; ++ni)
                b[ni] = *(const short8v*)&B[(n0 + ni * 16 + lr) * 256 + ka];
#pragma unroll
            for (int mi = 0; mi < 4; ++mi)
#pragma unroll
                for (int ni = 0; ni < 4; ++ni)
                    acc[mi][ni] = __builtin_amdgcn_mfma_f32_16x16x32_bf16(a[mi], b[ni], acc[mi][ni], 0, 0, 0);
        }
    }
#pragma unroll
    for (int mi = 0; mi < 4; ++mi)
#pragma unroll
        for (int ni = 0; ni < 4; ++ni) {
            int col = n0 + ni * 16 + lr;
            float bs = bias[col];
#pragma unroll
            for (int r = 0; r < 4; ++r) {
                int row = m0 + mi * 16 + (l >> 4) * 4 + r;
                float v = acc[mi][ni][r] + bs;
                if (TANH) v = tanhf(v);
                split_store(v, Chi, Clo, row * 256 + col);
            }
        }
}

// ---------------- split-bf16 MFMA LSTM, LDS-FREE ----------------
// Wave w owns dcols [by*64 + w*16, +16) and computes ALL 4 gates for them:
// acc[gate][mi]. All gate values for (row,d) are in the same lane -> register
// epilogue, no LDS exchange (round-9: 65KB LDS -> 2 blocks/CU -> latency-bound).
// Fragments loaded once per k-block, reused by the 3 split-bf16 terms.
template <bool FIRST>
__global__ __launch_bounds__(256) void mfma_lstm(const u16* __restrict__ Xh, const u16* __restrict__ Xl,
                                                 const u16* __restrict__ Hh, const u16* __restrict__ Hl,
                                                 const u16* __restrict__ Wih_h, const u16* __restrict__ Wih_l,
                                                 const u16* __restrict__ Whh_h, const u16* __restrict__ Whh_l,
                                                 const float* __restrict__ bih, const float* __restrict__ bhh,
                                                 const float* __restrict__ c_in, float* __restrict__ c_out,
                                                 u16* __restrict__ Ohi, u16* __restrict__ Olo) {
    const int l = threadIdx.x & 63, w = threadIdx.x >> 6;
    const int m0 = blockIdx.x * 64;
    const int dw = blockIdx.y * 64 + w * 16;  // this wave's 16 d-columns
    const int lr = l & 15, lk = (l >> 4) * 8;
    f32x4 acc[4][4];  // [gate][mi]
#pragma unroll
    for (int g = 0; g < 4; ++g)
#pragma unroll
        for (int mi = 0; mi < 4; ++mi) acc[g][mi] = (f32x4){0.f, 0.f, 0.f, 0.f};

    const int npass = FIRST ? 1 : 2;
    for (int pass = 0; pass < npass; ++pass) {
        const u16* Ih = pass ? Hh : Xh;
        const u16* Il = pass ? Hl : Xl;
        const u16* Wh = pass ? Whh_h : Wih_h;
        const u16* Wl = pass ? Whh_l : Wih_l;
#pragma unroll
        for (int kb = 0; kb < 8; ++kb) {
            int ka = kb * 32 + lk;
            short8v ah[4], al[4], bh[4], bl[4];
#pragma unroll
            for (int mi = 0; mi < 4; ++mi) {
                ah[mi] = *(const short8v*)&Ih[(m0 + mi * 16 + lr) * 256 + ka];
                al[mi] = *(const short8v*)&Il[(m0 + mi * 16 + lr) * 256 + ka];
            }
#pragma unroll
            for (int g = 0; g < 4; ++g) {
                bh[g] = *(const short8v*)&Wh[(g * 256 + dw + lr) * 256 + ka];
                bl[g] = *(const short8v*)&Wl[(g * 256 + dw + lr) * 256 + ka];
            }
#pragma unroll
            for (int g = 0; g < 4; ++g)
#pragma unroll
                for (int mi = 0; mi < 4; ++mi) {
                    acc[g][mi] = __builtin_amdgcn_mfma_f32_16x16x32_bf16(al[mi], bh[g], acc[g][mi], 0, 0, 0);
                    acc[g][mi] = __builtin_amdgcn_mfma_f32_16x16x32_bf16(ah[mi], bl[g], acc[g][mi], 0, 0, 0);
                    acc[g][mi] = __builtin_amdgcn_mfma_f32_16x16x32_bf16(ah[mi], bh[g], acc[g][mi], 0, 0, 0);
                }
        }
    }
    // register epilogue: C/D layout col=lane&15, row=(lane>>4)*4+reg
    const int d = dw + lr;
    const float bi0 = bih[d] + bhh[d];
    const float bi1 = bih[256 + d] + bhh[256 + d];
    const float bi2 = bih[512 + d] + bhh[512 + d];
    const float bi3 = bih[768 + d] + bhh[768 + d];
#pragma unroll
    for (int mi = 0; mi < 4; ++mi)
#pragma unroll
        for (int r = 0; r < 4; ++r) {
            int row = m0 + mi * 16 + (l >> 4) * 4 + r;
            float gi = acc[0][mi][r] + bi0;
            float gf = acc[1][mi][r] + bi1;
            float gg = acc[2][mi][r] + bi2;
            float go = acc[3][mi][r] + bi3;
            float cprev = FIRST ? 0.0f : c_in[row * 256 + d];
            float cv = sigf(gf) * cprev + sigf(gi) * tanhf(gg);
            float hv = sigf(go) * tanhf(cv);
            c_out[row * 256 + d] = cv;
            split_store(hv, Ohi, Olo, row * 256 + d);
        }
}

// ---------------- fp32 LSTM (graph-level only, M=64) ----------------
template <bool FIRST>
__global__ __launch_bounds__(256) void lstm_gemm(const float* __restrict__ X,
                                                 const float* __restrict__ H,
                                                 const float* __restrict__ Wih,
                                                 const float* __restrict__ Whh,
                                                 const float* __restrict__ bih,
                                                 const float* __restrict__ bhh,
                                                 const float* __restrict__ c_in,
                                                 float* __restrict__ c_out,
                                                 float* __restrict__ h_out, int M) {
    __shared__ float As[16][68];
    __shared__ float Bs[4][16][68];
    const int m0 = blockIdx.x * 64;
    const int n0 = blockIdx.y * 64;
    const int t = threadIdx.x;
    const int ty = t >> 4, tx = t & 15;
    const int lm = t >> 2;
    const int lk4 = (t & 3) * 4;
    float acc[4][4][4] = {};
    const int npass = FIRST ? 1 : 2;
    for (int pass = 0; pass < npass; ++pass) {
        const float* Ain = pass ? H : X;
        const float* W = pass ? Whh : Wih;
        for (int k0 = 0; k0 < 256; k0 += 16) {
            float4 av = *(const float4*)&Ain[(m0 + lm) * 256 + k0 + lk4];
            float4 w0 = *(const float4*)&W[(0 * 256 + n0 + lm) * 256 + k0 + lk4];
            float4 w1 = *(const float4*)&W[(1 * 256 + n0 + lm) * 256 + k0 + lk4];
            float4 w2 = *(const float4*)&W[(2 * 256 + n0 + lm) * 256 + k0 + lk4];
            float4 w3 = *(const float4*)&W[(3 * 256 + n0 + lm) * 256 + k0 + lk4];
            __syncthreads();
            As[lk4 + 0][lm] = av.x; As[lk4 + 1][lm] = av.y;
            As[lk4 + 2][lm] = av.z; As[lk4 + 3][lm] = av.w;
            Bs[0][lk4 + 0][lm] = w0.x; Bs[0][lk4 + 1][lm] = w0.y;
            Bs[0][lk4 + 2][lm] = w0.z; Bs[0][lk4 + 3][lm] = w0.w;
            Bs[1][lk4 + 0][lm] = w1.x; Bs[1][lk4 + 1][lm] = w1.y;
            Bs[1][lk4 + 2][lm] = w1.z; Bs[1][lk4 + 3][lm] = w1.w;
            Bs[2][lk4 + 0][lm] = w2.x; Bs[2][lk4 + 1][lm] = w2.y;
            Bs[2][lk4 + 2][lm] = w2.z; Bs[2][lk4 + 3][lm] = w2.w;
            Bs[3][lk4 + 0][lm] = w3.x; Bs[3][lk4 + 1][lm] = w3.y;
            Bs[3][lk4 + 2][lm] = w3.z; Bs[3][lk4 + 3][lm] = w3.w;
            __syncthreads();
#pragma unroll
            for (int kk = 0; kk < 16; ++kk) {
                float4 a = *(const float4*)&As[kk][ty * 4];
                float av4[4] = {a.x, a.y, a.z, a.w};
#pragma unroll
                for (int gg = 0; gg < 4; ++gg) {
                    float4 b = *(const float4*)&Bs[gg][kk][tx * 4];
                    float bv4[4] = {b.x, b.y, b.z, b.w};
#pragma unroll
                    for (int i = 0; i < 4; ++i)
#pragma unroll
                        for (int j = 0; j < 4; ++j)
                            acc[gg][i][j] = fmaf(av4[i], bv4[j], acc[gg][i][j]);
                }
            }
        }
    }
#pragma unroll
    for (int i = 0; i < 4; ++i) {
        int r = m0 + ty * 4 + i;
#pragma unroll
        for (int j = 0; j < 4; ++j) {
            int dcol = n0 + tx * 4 + j;
            float gi = acc[0][i][j] + bih[dcol] + bhh[dcol];
            float gf = acc[1][i][j] + bih[256 + dcol] + bhh[256 + dcol];
            float gg = acc[2][i][j] + bih[512 + dcol] + bhh[512 + dcol];
            float go = acc[3][i][j] + bih[768 + dcol] + bhh[768 + dcol];
            float cprev = FIRST ? 0.0f : c_in[r * 256 + dcol];
            float cv = sigf(gf) * cprev + sigf(gi) * tanhf(gg);
            float hv = sigf(go) * tanhf(cv);
            c_out[r * 256 + dcol] = cv;
            h_out[r * 256 + dcol] = hv;
        }
    }
}

// ---------------- CSR build ----------------
__global__ __launch_bounds__(256) void csr_init(int* __restrict__ counts, float* __restrict__ deg) {
    int i = blockIdx.x * 256 + threadIdx.x;
    counts[i] = 0;
    deg[i] = 1.0f;
}
__global__ __launch_bounds__(256) void csr_hist(const int* __restrict__ dst,
                                                const float* __restrict__ ew,
                                                int* __restrict__ counts,
                                                float* __restrict__ deg) {
    int e = blockIdx.x * 256 + threadIdx.x;
    int d = dst[e];
    atomicAdd(&counts[d], 1);
    atomicAdd(&deg[d], ew[e]);
}
__global__ __launch_bounds__(256) void csr_dinv(float* __restrict__ deg) {
    int i = blockIdx.x * 256 + threadIdx.x;
    deg[i] = 1.0f / sqrtf(deg[i]);
}
__global__ __launch_bounds__(256) void csr_scan(const int* __restrict__ counts,
                                                int* __restrict__ offs,
                                                int* __restrict__ cursor) {
    __shared__ int part[256];
    int t = threadIdx.x;
    int base = t * 128;
    int s = 0;
    for (int k = 0; k < 128; ++k) s += counts[base + k];
    part[t] = s;
    __syncthreads();
    for (int off = 1; off < 256; off <<= 1) {
        int v = part[t];
        int add = (t >= off) ? part[t - off] : 0;
        __syncthreads();
        part[t] = v + add;
        __syncthreads();
    }
    int run = part[t] - s;
    for (int k = 0; k < 128; ++k) {
        int c = counts[base + k];
        offs[base + k] = run;
        cursor[base + k] = run;
        run += c;
    }
    if (t == 255) offs[NODES] = run;
}
__global__ __launch_bounds__(256) void csr_fill(const int* __restrict__ src,
                                                const int* __restrict__ dst,
                                                const float* __restrict__ ew,
                                                const float* __restrict__ dinv,
                                                int* __restrict__ cursor,
                                                int* __restrict__ es,
                                                float* __restrict__ en) {
    int e = blockIdx.x * 256 + threadIdx.x;
    int s = src[e], d = dst[e];
    int pos = atomicAdd(&cursor[d], 1);
    es[pos] = s;
    en[pos] = dinv[s] * ew[e] * dinv[d];
}

// ---------------- GCN gather (split in, split out) ----------------
__global__ __launch_bounds__(256) void gcn_gather(const u16* __restrict__ xh, const u16* __restrict__ xl,
                                                  const int* __restrict__ offs,
                                                  const int* __restrict__ es,
                                                  const float* __restrict__ en,
                                                  const float* __restrict__ dinv,
                                                  u16* __restrict__ oh, u16* __restrict__ ol) {
    int i = blockIdx.x, d = threadIdx.x;
    float di = dinv[i];
    float acc = di * di * (bfu(xh[i * DD + d]) + bfu(xl[i * DD + d]));
    int a = offs[i], b = offs[i + 1];
    for (int j = a; j < b; ++j) {
        int s = es[j];
        float w = en[j];
        acc += w * (bfu(xh[s * DD + d]) + bfu(xl[s * DD + d]));
    }
    split_store(acc, oh, ol, i * DD + d);
}

// ---------------- pooling (split x) ----------------
__global__ __launch_bounds__(256) void score_kernel(const u16* __restrict__ hh, const u16* __restrict__ hl,
                                                    const float* __restrict__ Wp2,
                                                    const float* __restrict__ mask_score,
                                                    float* __restrict__ score) {
    int m = blockIdx.x * 4 + (threadIdx.x >> 6);
    int l = threadIdx.x & 63;
    ushort4 a = *(const ushort4*)&hh[m * DD + l * 4];
    ushort4 b = *(const ushort4*)&hl[m * DD + l * 4];
    float4 w = *(const float4*)&Wp2[l * 4];
    float d = (bfu(a.x) + bfu(b.x)) * w.x + (bfu(a.y) + bfu(b.y)) * w.y +
              (bfu(a.z) + bfu(b.z)) * w.z + (bfu(a.w) + bfu(b.w)) * w.w;
#pragma unroll
    for (int off = 32; off; off >>= 1) d += __shfl_down(d, off);
    if (l == 0) score[m] = d + mask_score[m];
}

__global__ __launch_bounds__(256) void pool_kernel(const u16* __restrict__ xh, const u16* __restrict__ xl,
                                                   const float* __restrict__ score,
                                                   float* __restrict__ gout) {
    int b = blockIdx.x;
    int t = threadIdx.x;
    __shared__ float sal[512];
    __shared__ float wred[4];
    __shared__ float sbc[2];
    int lane = t & 63, wv = t >> 6;
    float s0 = score[b * SEQ + t];
    float s1 = score[b * SEQ + 256 + t];
    float m = fmaxf(s0, s1);
#pragma unroll
    for (int off = 32; off; off >>= 1) m = fmaxf(m, __shfl_down(m, off));
    if (lane == 0) wred[wv] = m;
    __syncthreads();
    if (t == 0) sbc[0] = fmaxf(fmaxf(wred[0], wred[1]), fmaxf(wred[2], wred[3]));
    __syncthreads();
    float mx = sbc[0];
    float e0 = expf(s0 - mx), e1 = expf(s1 - mx);
    sal[t] = e0;
    sal[t + 256] = e1;
    float sm = e0 + e1;
#pragma unroll
    for (int off = 32; off; off >>= 1) sm += __shfl_down(sm, off);
    __syncthreads();
    if (lane == 0) wred[wv] = sm;
    __syncthreads();
    if (t == 0) sbc[1] = wred[0] + wred[1] + wred[2] + wred[3];
    __syncthreads();
    float inv = 1.0f / sbc[1];
    float accv = 0.0f;
    size_t base = (size_t)b * SEQ * DD + t;
    for (int n = 0; n < SEQ; ++n)
        accv += sal[n] * (bfu(xh[base + (size_t)n * DD]) + bfu(xl[base + (size_t)n * DD]));
    gout[b * DD + t] = accv * inv;
}

// ---------------- final: out = tanh(x2) * mask_pad ----------------
__global__ __launch_bounds__(256) void final_kernel(const u16* __restrict__ xh, const u16* __restrict__ xl,
                                                    const float* __restrict__ mask_pad,
                                                    float* __restrict__ out) {
    int i = blockIdx.x, d = threadIdx.x;
    float v = bfu(xh[i * DD + d]) + bfu(xl[i * DD + d]);
    out[i * DD + d] = tanhf(v) * mask_pad[i];
}

extern "C" void kernel_launch(void* const* d_in, const int* in_sizes, int n_in,
                              void* d_out, int out_size, void* d_ws, size_t ws_size,
                              hipStream_t stream) {
    const int* x_tokens = (const int*)d_in[0];
    const int* word_type = (const int*)d_in[1];
    const int* edge_src = (const int*)d_in[2];
    const int* edge_dst = edge_src + NE;
    const float* edge_attr = (const float*)d_in[3];
    const float* mask_pad = (const float*)d_in[4];
    const float* mask_score = (const float*)d_in[5];
    const float* emb = (const float*)d_in[6];
    const float* wt = (const float*)d_in[7];
    const float* W_w = (const float*)d_in[8];
    const float* b_w = (const float*)d_in[9];
    const float* W_g1 = (const float*)d_in[10];
    const float* b_g1 = (const float*)d_in[11];
    const float* W_g2 = (const float*)d_in[12];
    const float* b_g2 = (const float*)d_in[13];
    const float* W_p1 = (const float*)d_in[14];
    const float* b_p1 = (const float*)d_in[15];
    const float* W_p2 = (const float*)d_in[16];
    const float* Wih_x = (const float*)d_in[17];
    const float* Whh_x = (const float*)d_in[18];
    const float* bih_x = (const float*)d_in[19];
    const float* bhh_x = (const float*)d_in[20];
    const float* Wih_g = (const float*)d_in[21];
    const float* Whh_g = (const float*)d_in[22];
    const float* bih_g = (const float*)d_in[23];
    const float* bhh_g = (const float*)d_in[24];

    float* out = (float*)d_out;
    char* ws = (char*)d_ws;

    // ---- smalls / CSR / weight-splits in first 8 MB ----
    int* counts = (int*)ws;
    int* cursor = counts + NODES;
    int* offs = cursor + NODES;
    float* dinv = (float*)(offs + NODES + 64);
    float* score = dinv + NODES;
    float* g1 = score + NODES;
    float* g2 = g1 + BATCH * DD;
    float* hg = g2 + BATCH * DD;
    float* cg = hg + BATCH * DD;
    int* es = (int*)(cg + BATCH * DD);
    float* en = (float*)(es + NE);
    u16* wsm = (u16*)(en + NE);
    u16* wwTh = wsm;               u16* wwTl = wwTh + 65536;
    u16* wg1h = wwTl + 65536;      u16* wg1l = wg1h + 65536;
    u16* wg2h = wg1l + 65536;      u16* wg2l = wg2h + 65536;
    u16* wp1h = wg2l + 65536;      u16* wp1l = wp1h + 65536;
    u16* wihh = wp1l + 65536;      u16* wihl = wihh + 262144;
    u16* whhh = wihl + 262144;     u16* whhl = whhh + 262144;

    // ---- split node buffers (hi plane | lo plane) ----
    const size_t NDf = (size_t)NODES * DD;
    u16* base = (u16*)(ws + (8u << 20));
    u16* S1h = base;               u16* S1l = S1h + NDf;
    u16* S2h = S1l + NDf;          u16* S2l = S2h + NDf;
    u16* S3h = S2l + NDf;          u16* S3l = S3h + NDf;
    float* OUTB = out;  // fp32 c-state scratch in x_out region; final overwrites

    dim3 blk(256);
    dim3 gemmGrid(NODES / 64);
    dim3 lstmGrid(NODES / 64, 4);

    // CSR build
    csr_init<<<NODES / 256, blk, 0, stream>>>(counts, dinv);
    csr_hist<<<NE / 256, blk, 0, stream>>>(edge_dst, edge_attr, counts, dinv);
    csr_dinv<<<NODES / 256, blk, 0, stream>>>(dinv);
    csr_scan<<<1, blk, 0, stream>>>(counts, offs, cursor);
    csr_fill<<<NE / 256, blk, 0, stream>>>(edge_src, edge_dst, edge_attr, dinv, cursor, es, en);

    // weight splits
    wsplitT<<<256, blk, 0, stream>>>(W_w, wwTh, wwTl);
    wsplitT<<<256, blk, 0, stream>>>(W_g1, wg1h, wg1l);
    wsplitT<<<256, blk, 0, stream>>>(W_g2, wg2h, wg2l);
    wsplitT<<<256, blk, 0, stream>>>(W_p1, wp1h, wp1l);
    wsplit<<<1024, blk, 0, stream>>>(Wih_x, wihh, wihl);
    wsplit<<<1024, blk, 0, stream>>>(Whh_x, whhh, whhl);

    // x_emb -> S1
    embed_split<<<NODES, blk, 0, stream>>>(x_tokens, word_type, emb, wt, S1h, S1l);
    // x0 = x_emb @ W_w + b_w -> S2
    mfma_gemm<false><<<gemmGrid, blk, 0, stream>>>(S1h, S1l, wwTh, wwTl, b_w, S2h, S2l);
    // agg0 -> S1
    gcn_gather<<<NODES, blk, 0, stream>>>(S2h, S2l, offs, es, en, dinv, S1h, S1l);
    // x1_mid = agg0 @ W_g1 + b_g1 -> S3
    mfma_gemm<false><<<gemmGrid, blk, 0, stream>>>(S1h, S1l, wg1h, wg1l, b_g1, S3h, S3l);
    // LSTM1 cell1(x0=S2) -> h1:S1, c1:OUTB
    mfma_lstm<true><<<lstmGrid, blk, 0, stream>>>(S2h, S2l, nullptr, nullptr, wihh, wihl, whhh, whhl,
                                                  bih_x, bhh_x, nullptr, OUTB, S1h, S1l);
    // LSTM1 cell2(x1_mid=S3, h1=S1) -> x1:S2, c:OUTB
    mfma_lstm<false><<<lstmGrid, blk, 0, stream>>>(S3h, S3l, S1h, S1l, wihh, wihl, whhh, whhl,
                                                   bih_x, bhh_x, OUTB, OUTB, S2h, S2l);
    // pool 1
    mfma_gemm<true><<<gemmGrid, blk, 0, stream>>>(S2h, S2l, wp1h, wp1l, b_p1, S3h, S3l);
    score_kernel<<<NODES / 4, blk, 0, stream>>>(S3h, S3l, W_p2, mask_score, score);
    pool_kernel<<<BATCH, blk, 0, stream>>>(S2h, S2l, score, g1);
    // agg1 -> S1
    gcn_gather<<<NODES, blk, 0, stream>>>(S2h, S2l, offs, es, en, dinv, S1h, S1l);
    // x2_mid = agg1 @ W_g2 + b_g2 -> S3
    mfma_gemm<false><<<gemmGrid, blk, 0, stream>>>(S1h, S1l, wg2h, wg2l, b_g2, S3h, S3l);
    // LSTM2 cell1(x1=S2) -> h2:S1, c2:OUTB
    mfma_lstm<true><<<lstmGrid, blk, 0, stream>>>(S2h, S2l, nullptr, nullptr, wihh, wihl, whhh, whhl,
                                                  bih_x, bhh_x, nullptr, OUTB, S1h, S1l);
    // LSTM2 cell2(x2_mid=S3, h2=S1) -> x2:S2, c:OUTB
    mfma_lstm<false><<<lstmGrid, blk, 0, stream>>>(S3h, S3l, S1h, S1l, wihh, wihl, whhh, whhl,
                                                   bih_x, bhh_x, OUTB, OUTB, S2h, S2l);
    // pool 2
    mfma_gemm<true><<<gemmGrid, blk, 0, stream>>>(S2h, S2l, wp1h, wp1l, b_p1, S3h, S3l);
    score_kernel<<<NODES / 4, blk, 0, stream>>>(S3h, S3l, W_p2, mask_score, score);
    pool_kernel<<<BATCH, blk, 0, stream>>>(S2h, S2l, score, g2);
    // graph-level LSTM (fp32, tiny)
    lstm_gemm<true><<<dim3(1, 4), blk, 0, stream>>>(g1, nullptr, Wih_g, Whh_g, bih_g, bhh_g,
                                                    nullptr, cg, hg, BATCH);
    lstm_gemm<false><<<dim3(1, 4), blk, 0, stream>>>(g2, hg, Wih_g, Whh_g, bih_g, bhh_g,
                                                     cg, cg, out + NODES * DD, BATCH);
    // x_out
    final_kernel<<<NODES, blk, 0, stream>>>(S2h, S2l, mask_pad, out);
}